// Round 18
// baseline (55.055 us; speedup 1.0000x reference)
//
#include <hip/hip_runtime.h>

// GMP via MFMA (r13 champion) + a 16x-looped PROFILING PROBE writing to
// d_ws so the steady-state tile cost shows up in rocprof's top-5 with
// counters (the 11us main kernel is invisible behind ~39us harness
// fills). Probe = Q-build + MFMA groups + combine, per-iter sample
// shift, accumulators kept live. Decomposition next round:
//   probe_dur/16 = steady tile cost;  main_dur - that = fixed overhead.

typedef short short8 __attribute__((ext_vector_type(8)));
typedef float f32x4 __attribute__((ext_vector_type(4)));

constexpr int S_FIXED = 16384;
constexpr int BLK = 256;          // 4 waves
constexpr int TILE = 512;         // samples per block (128 per wave)
constexpr int GROUPS = 9;         // 16-position MFMA groups per wave
constexpr int IMAX = 143;         // reversed-table top index
constexpr int QRN = 160;          // qr entries per wave
constexpr int WLW = 148;          // wl row width (floats)
constexpr int PITERS = 16;        // probe iterations

__device__ __forceinline__ unsigned short bfc(float f) {
    union { float f; unsigned u; } v; v.f = f;
    const unsigned u = v.u;
    return (unsigned short)((u + 0x7FFFu + ((u >> 16) & 1u)) >> 16);
}

__device__ __forceinline__ short8 mk8(ushort4 lo, ushort4 hi) {
    union { ushort4 u[2]; short8 s; } x;
    x.u[0] = lo; x.u[1] = hi;
    return x.s;
}

// ---------------- production kernel: r13 verbatim ----------------
__global__ __launch_bounds__(BLK) void gmp_mfma(
    const float* __restrict__ x, const float* __restrict__ a,
    const float* __restrict__ b, float* __restrict__ out, int S)
{
    __shared__ alignas(16) unsigned short th[16][64];
    __shared__ alignas(16) ushort4 qr[4][QRN];
    __shared__ alignas(16) float wl[4][10][WLW];

    const int t = threadIdx.x;
    const int wid = t >> 6, lane = t & 63;
    const int m = lane & 15, h = lane >> 4;
    const int blocksPerRow = S / TILE;
    const int brow = blockIdx.x / blocksPerRow;
    const int s0   = (blockIdx.x % blocksPerRow) * TILE;
    const int s0w  = s0 + 128 * wid;
    const int vb   = s0w - 12;

    for (int idx = t; idx < 1024; idx += BLK) {
        const int col = idx >> 6, f = idx & 63;
        float v = 0.f;
        if (col < 10 && f < 44) {
            const int j = f >> 2, c = f & 3;
            if (j == 0) { if (c < 3) v = a[(c + 1) * 10 + (9 - col)]; }
            else v = b[c * 100 + col * 10 + (j - 1)];
        }
        th[col][f] = bfc(v);
    }

    const float2* __restrict__ xr2 =
        reinterpret_cast<const float2*>(x) + (size_t)brow * S;
    for (int i = lane; i < QRN; i += 64) {
        const int p = vb + IMAX - i;
        float xre = 0.f, xim = 0.f;
        if (p >= 0 && p < S) { const float2 v = xr2[p]; xre = v.x; xim = v.y; }
        const float m2 = xre * xre + xim * xim;
        const float r  = __builtin_amdgcn_sqrtf(m2);
        ushort4 q;
        q.x = bfc(r); q.y = bfc(m2); q.z = bfc(m2 * r); q.w = bfc(m2 * m2);
        qr[wid][i] = q;
    }
    __syncthreads();

    const short8 bfr0 = *reinterpret_cast<const short8*>(&th[m][8 * h]);
    const short8 bfr1 = *reinterpret_cast<const short8*>(&th[m][8 * h + 32]);

    #pragma unroll
    for (int g = 0; g < GROUPS; ++g) {
        const int i1 = IMAX - 16 * g - m + 2 * h;
        const short8 af0 = mk8(qr[wid][i1],     qr[wid][i1 + 1]);
        const short8 af1 = mk8(qr[wid][i1 + 8], qr[wid][i1 + 9]);
        f32x4 acc = {0.f, 0.f, 0.f, 0.f};
        acc = __builtin_amdgcn_mfma_f32_16x16x32_bf16(af0, bfr0, acc, 0, 0, 0);
        acc = __builtin_amdgcn_mfma_f32_16x16x32_bf16(af1, bfr1, acc, 0, 0, 0);
        if (m < 10)
            *reinterpret_cast<f32x4*>(&wl[wid][m][16 * g + 4 * h]) = acc;
    }

    const int sa0 = s0w + 2 * lane;
    const float4* __restrict__ xr4 =
        reinterpret_cast<const float4*>(x) + (size_t)brow * (S / 2);
    float xf[24];
    {
        const int base4 = (sa0 - 10) / 2;
        #pragma unroll
        for (int n = 0; n < 6; ++n) {
            int idx = base4 + n;
            if (idx < 0) idx = 0;
            const float4 f4 = xr4[idx];
            xf[4 * n + 0] = f4.x; xf[4 * n + 1] = f4.y;
            xf[4 * n + 2] = f4.z; xf[4 * n + 3] = f4.w;
        }
    }
    float yr0 = 0.f, yi0 = 0.f, yr1 = 0.f, yi1 = 0.f;
    #pragma unroll
    for (int l = 0; l < 10; ++l) {
        const float bl = a[9 - l];
        const float w0 = wl[wid][l][2 * lane + 12 - l] + bl;
        const float w1 = wl[wid][l][2 * lane + 13 - l] + bl;
        const int wp = 10 - l;
        yr0 += w0 * xf[2 * wp];     yi0 += w0 * xf[2 * wp + 1];
        yr1 += w1 * xf[2 * wp + 2]; yi1 += w1 * xf[2 * wp + 3];
    }
    const bool k0 = sa0 >= 20, k1 = (sa0 + 1) >= 20;
    const float4 o = make_float4(k0 ? yr0 : 0.f, k0 ? yi0 : 0.f,
                                 k1 ? yr1 : 0.f, k1 ? yi1 : 0.f);
    reinterpret_cast<float4*>(out)[((size_t)brow * S + sa0) / 2] = o;
}

// ---------------- profiling probe: 16x steady-state tile body ----------------
__global__ __launch_bounds__(BLK) void gmp_probe(
    const float* __restrict__ x, const float* __restrict__ a,
    const float* __restrict__ b, float* __restrict__ ws,
    unsigned long long ws_bytes, int S)
{
    __shared__ alignas(16) unsigned short th[16][64];
    __shared__ alignas(16) ushort4 qr[4][QRN];
    __shared__ alignas(16) float wl[4][10][WLW];

    const int t = threadIdx.x;
    const int wid = t >> 6, lane = t & 63;
    const int m = lane & 15, h = lane >> 4;
    const int blocksPerRow = S / TILE;
    const int brow = blockIdx.x / blocksPerRow;
    const int s0   = (blockIdx.x % blocksPerRow) * TILE;

    // Theta once (fixed per-block cost deliberately excluded from loop)
    for (int idx = t; idx < 1024; idx += BLK) {
        const int col = idx >> 6, f = idx & 63;
        float v = 0.f;
        if (col < 10 && f < 44) {
            const int j = f >> 2, c = f & 3;
            if (j == 0) { if (c < 3) v = a[(c + 1) * 10 + (9 - col)]; }
            else v = b[c * 100 + col * 10 + (j - 1)];
        }
        th[col][f] = bfc(v);
    }
    __syncthreads();

    const short8 bfr0 = *reinterpret_cast<const short8*>(&th[m][8 * h]);
    const short8 bfr1 = *reinterpret_cast<const short8*>(&th[m][8 * h + 32]);

    const float2* __restrict__ xr2 =
        reinterpret_cast<const float2*>(x) + (size_t)brow * S;
    const float4* __restrict__ xr4 =
        reinterpret_cast<const float4*>(x) + (size_t)brow * (S / 2);

    float aR0 = 0.f, aI0 = 0.f, aR1 = 0.f, aI1 = 0.f;

    #pragma unroll 1
    for (int r = 0; r < PITERS; ++r) {
        const int s0w = s0 + 128 * wid + 32 * r;   // per-iter shift
        const int vb  = s0w - 12;

        // Q build (qr per-wave; same-wave LDS ops are in-order -> no barrier)
        for (int i = lane; i < QRN; i += 64) {
            const int p = vb + IMAX - i;
            float xre = 0.f, xim = 0.f;
            if (p >= 0 && p < S) { const float2 v = xr2[p]; xre = v.x; xim = v.y; }
            const float m2 = xre * xre + xim * xim;
            const float rr = __builtin_amdgcn_sqrtf(m2);
            ushort4 q;
            q.x = bfc(rr); q.y = bfc(m2); q.z = bfc(m2 * rr); q.w = bfc(m2 * m2);
            qr[wid][i] = q;
        }

        #pragma unroll
        for (int g = 0; g < GROUPS; ++g) {
            const int i1 = IMAX - 16 * g - m + 2 * h;
            const short8 af0 = mk8(qr[wid][i1],     qr[wid][i1 + 1]);
            const short8 af1 = mk8(qr[wid][i1 + 8], qr[wid][i1 + 9]);
            f32x4 acc = {0.f, 0.f, 0.f, 0.f};
            acc = __builtin_amdgcn_mfma_f32_16x16x32_bf16(af0, bfr0, acc, 0, 0, 0);
            acc = __builtin_amdgcn_mfma_f32_16x16x32_bf16(af1, bfr1, acc, 0, 0, 0);
            if (m < 10)
                *reinterpret_cast<f32x4*>(&wl[wid][m][16 * g + 4 * h]) = acc;
        }

        const int sa0 = s0w + 2 * lane;
        float xf[24];
        {
            const int base4 = (sa0 - 10) / 2;
            #pragma unroll
            for (int n = 0; n < 6; ++n) {
                int idx = base4 + n;
                if (idx < 0) idx = 0;
                if (idx > S / 2 - 1) idx = S / 2 - 1;   // shift-safe clamp
                const float4 f4 = xr4[idx];
                xf[4 * n + 0] = f4.x; xf[4 * n + 1] = f4.y;
                xf[4 * n + 2] = f4.z; xf[4 * n + 3] = f4.w;
            }
        }
        float yr0 = 0.f, yi0 = 0.f, yr1 = 0.f, yi1 = 0.f;
        #pragma unroll
        for (int l = 0; l < 10; ++l) {
            const float bl = a[9 - l];
            const float w0 = wl[wid][l][2 * lane + 12 - l] + bl;
            const float w1 = wl[wid][l][2 * lane + 13 - l] + bl;
            const int wp = 10 - l;
            yr0 += w0 * xf[2 * wp];     yi0 += w0 * xf[2 * wp + 1];
            yr1 += w1 * xf[2 * wp + 2]; yi1 += w1 * xf[2 * wp + 3];
        }
        aR0 += yr0; aI0 += yi0; aR1 += yr1; aI1 += yi1;
    }

    // keep the whole loop live regardless of ws size (rule #17)
    asm volatile("" :: "v"(aR0), "v"(aI0), "v"(aR1), "v"(aI1));
    const unsigned long long gid =
        (unsigned long long)blockIdx.x * BLK + t;
    if ((gid + 1) * 16ull <= ws_bytes) {
        float4 o = make_float4(aR0, aI0, aR1, aI1);
        reinterpret_cast<float4*>(ws)[gid] = o;
    }
}

extern "C" void kernel_launch(void* const* d_in, const int* in_sizes, int n_in,
                              void* d_out, int out_size, void* d_ws, size_t ws_size,
                              hipStream_t stream) {
    const float* x = (const float*)d_in[0];
    const float* a = (const float*)d_in[1];
    const float* b = (const float*)d_in[2];
    float* out = (float*)d_out;

    const int S = S_FIXED;
    const int B = in_sizes[0] / (2 * S);
    const int nblocks = B * (S / TILE);

    gmp_mfma<<<dim3(nblocks), dim3(BLK), 0, stream>>>(x, a, b, out, S);
    gmp_probe<<<dim3(nblocks), dim3(BLK), 0, stream>>>(
        x, a, b, (float*)d_ws, (unsigned long long)ws_size, S);
}

// Round 19
// 11.362 us; speedup vs baseline: 4.8455x; 4.8455x over previous
//
#include <hip/hip_runtime.h>

// GMP via MFMA: y[s] = sum_l (W[s-l,l] + a0[l]) * x[s-l], masked s<20.
// W[v,l] = sum_f Phi[v][f] * Theta[f][l]  (GEMM, K=64 padded)
//   Phi[v][4j+c] = q_{c+1}[v-j], j=0..10 valid    q_k = |x|^k
//   Theta[4*0+c][l] = a[c+1][9-l] (c<3), 0 for c=3
//   Theta[4(1+m)+c][l] = b[c][l][m], m=0..9;  f>=44 or l>=10 -> 0
//   bias a0[l] = a[0][9-l] added in the combine epilogue.
//
// Round-19 (r13 base): cold-HBM latency overlap + Q VMEM diet.
//  (1) ALL global x loads issued at kernel top (combine window + Q pairs)
//      so first-touch ~900cyc latency hides under the Theta build.
//  (2) Q-build as paired float4 (1.25 loads/lane vs 2.5 float2); pair n
//      covers entries (2n, 2n+1) = positions (vb+143-2n, vb+142-2n).
//      Clamped garbage proven safe: high-side clamp touches entries i<=3
//      which feed only wl positions >=140 (never read; max used is 139);
//      low-side feeds masked s<20 outputs.
//  (3) v_cvt_pk_bf16_f32 packing + one 16B ds_write per pair.

typedef short short8 __attribute__((ext_vector_type(8)));
typedef float f32x4 __attribute__((ext_vector_type(4)));

constexpr int S_FIXED = 16384;
constexpr int BLK = 256;          // 4 waves
constexpr int TILE = 512;         // samples per block (128 per wave)
constexpr int GROUPS = 9;         // 16-position MFMA groups per wave
constexpr int IMAX = 143;         // reversed-table top index
constexpr int QRN = 160;          // qr entries per wave
constexpr int WLW = 148;          // wl row width (floats)

__device__ __forceinline__ unsigned short bfc(float f) {
    union { float f; unsigned u; } v; v.f = f;
    const unsigned u = v.u;
    return (unsigned short)((u + 0x7FFFu + ((u >> 16) & 1u)) >> 16);
}

// RNE-pack two floats into a packed bf16 pair (lo | hi<<16).
__device__ __forceinline__ unsigned cvtpk(float lo, float hi) {
    unsigned r;
    asm("v_cvt_pk_bf16_f32 %0, %1, %2" : "=v"(r) : "v"(lo), "v"(hi));
    return r;
}

__device__ __forceinline__ short8 mk8(ushort4 lo, ushort4 hi) {
    union { ushort4 u[2]; short8 s; } x;
    x.u[0] = lo; x.u[1] = hi;
    return x.s;
}

__global__ __launch_bounds__(BLK) void gmp_mfma(
    const float* __restrict__ x,   // (B, S, 2)
    const float* __restrict__ a,   // (4, 10)
    const float* __restrict__ b,   // (4, 10, 10)
    float* __restrict__ out,       // (B, S, 2)
    int S)
{
    __shared__ alignas(16) unsigned short th[16][64];   // Theta[col=l][f] bf16
    __shared__ alignas(16) ushort4 qr[4][QRN];          // per-wave reversed quads
    __shared__ alignas(16) float wl[4][10][WLW];        // per-wave W[l][pos-idx]

    const int t = threadIdx.x;
    const int wid = t >> 6, lane = t & 63;
    const int m = lane & 15, h = lane >> 4;
    const int blocksPerRow = S / TILE;                  // 32
    const int brow = blockIdx.x / blocksPerRow;
    const int s0   = (blockIdx.x % blocksPerRow) * TILE;
    const int s0w  = s0 + 128 * wid;                    // this wave's samples
    const int vb   = s0w - 12;                          // position base

    const float4* __restrict__ xr4 =
        reinterpret_cast<const float4*>(x) + (size_t)brow * (S / 2);

    // ---- EARLY: combine x-window loads (cold-HBM overlap w/ Theta) ----
    const int sa0 = s0w + 2 * lane;
    float xf[24];   // complex window [sa0-10, sa0+2)
    {
        const int base4 = (sa0 - 10) / 2;   // sa0 even -> exact
        #pragma unroll
        for (int n = 0; n < 6; ++n) {
            int idx = base4 + n;
            if (idx < 0) idx = 0;           // garbage -> masked s<20 only
            const float4 f4 = xr4[idx];
            xf[4 * n + 0] = f4.x; xf[4 * n + 1] = f4.y;
            xf[4 * n + 2] = f4.z; xf[4 * n + 3] = f4.w;
        }
    }

    // ---- EARLY: Q-pair loads. Pair n -> float4 idx (vb+142-2n)/2 ----
    float4 qx0, qx1;
    {
        int i40 = (vb + 142 - 2 * lane) / 2;            // vb even -> exact
        if (i40 < 0) i40 = 0;
        if (i40 > S / 2 - 1) i40 = S / 2 - 1;           // clamp: see header
        qx0 = xr4[i40];
        if (lane < 16) {
            int i41 = (vb + 142 - 2 * (64 + lane)) / 2;
            if (i41 < 0) i41 = 0;
            if (i41 > S / 2 - 1) i41 = S / 2 - 1;
            qx1 = xr4[i41];
        }
    }

    // ---- Theta build (block-wide, 1024 entries; r13 form) ----
    for (int idx = t; idx < 1024; idx += BLK) {
        const int col = idx >> 6, f = idx & 63;
        float v = 0.f;
        if (col < 10 && f < 44) {            // j <= 10 only
            const int j = f >> 2, c = f & 3;
            if (j == 0) { if (c < 3) v = a[(c + 1) * 10 + (9 - col)]; }
            else v = b[c * 100 + col * 10 + (j - 1)];
        }
        th[col][f] = bfc(v);
    }

    // ---- Q quads: pack + one 16B write per pair ----
    // entry 2n   = quads(f.z, f.w)  [position vb+143-2n]
    // entry 2n+1 = quads(f.x, f.y)  [position vb+142-2n]
    {
        const float m2a = qx0.z * qx0.z + qx0.w * qx0.w;
        const float ra  = __builtin_amdgcn_sqrtf(m2a);
        const float m2b = qx0.x * qx0.x + qx0.y * qx0.y;
        const float rb  = __builtin_amdgcn_sqrtf(m2b);
        uint4 o;
        o.x = cvtpk(ra, m2a);        o.y = cvtpk(m2a * ra, m2a * m2a);
        o.z = cvtpk(rb, m2b);        o.w = cvtpk(m2b * rb, m2b * m2b);
        *reinterpret_cast<uint4*>(&qr[wid][2 * lane]) = o;
        if (lane < 16) {
            const float m2c = qx1.z * qx1.z + qx1.w * qx1.w;
            const float rc  = __builtin_amdgcn_sqrtf(m2c);
            const float m2d = qx1.x * qx1.x + qx1.y * qx1.y;
            const float rd  = __builtin_amdgcn_sqrtf(m2d);
            uint4 o2;
            o2.x = cvtpk(rc, m2c);   o2.y = cvtpk(m2c * rc, m2c * m2c);
            o2.z = cvtpk(rd, m2d);   o2.w = cvtpk(m2d * rd, m2d * m2d);
            *reinterpret_cast<uint4*>(&qr[wid][128 + 2 * lane]) = o2;
        }
    }
    __syncthreads();   // th visible to all waves (qr is wave-private)

    // ---- B fragments (coefficients; once per wave) ----
    const short8 bfr0 = *reinterpret_cast<const short8*>(&th[m][8 * h]);
    const short8 bfr1 = *reinterpret_cast<const short8*>(&th[m][8 * h + 32]);

    // ---- MFMA: GROUPS groups of 16 positions; W -> LDS ----
    #pragma unroll
    for (int g = 0; g < GROUPS; ++g) {
        const int i1 = IMAX - 16 * g - m + 2 * h;
        const short8 af0 = mk8(qr[wid][i1],     qr[wid][i1 + 1]);
        const short8 af1 = mk8(qr[wid][i1 + 8], qr[wid][i1 + 9]);
        f32x4 acc = {0.f, 0.f, 0.f, 0.f};
        acc = __builtin_amdgcn_mfma_f32_16x16x32_bf16(af0, bfr0, acc, 0, 0, 0);
        acc = __builtin_amdgcn_mfma_f32_16x16x32_bf16(af1, bfr1, acc, 0, 0, 0);
        // D: col = lane&15 (= l), rows (lane>>4)*4 + r (= position offset)
        if (m < 10)
            *reinterpret_cast<f32x4*>(&wl[wid][m][16 * g + 4 * h]) = acc;
    }

    // ---- combine epilogue: 2 samples per lane (xf preloaded) ----
    float yr0 = 0.f, yi0 = 0.f, yr1 = 0.f, yi1 = 0.f;
    #pragma unroll
    for (int l = 0; l < 10; ++l) {
        const float bl = a[9 - l];                       // a[0][9-l]
        const float w0 = wl[wid][l][2 * lane + 12 - l] + bl;
        const float w1 = wl[wid][l][2 * lane + 13 - l] + bl;
        const int wp = 10 - l;                           // window pos, j=0
        yr0 += w0 * xf[2 * wp];     yi0 += w0 * xf[2 * wp + 1];
        yr1 += w1 * xf[2 * wp + 2]; yi1 += w1 * xf[2 * wp + 3];
    }
    const bool k0 = sa0 >= 20, k1 = (sa0 + 1) >= 20;
    const float4 o = make_float4(k0 ? yr0 : 0.f, k0 ? yi0 : 0.f,
                                 k1 ? yr1 : 0.f, k1 ? yi1 : 0.f);
    reinterpret_cast<float4*>(out)[((size_t)brow * S + sa0) / 2] = o;
}

extern "C" void kernel_launch(void* const* d_in, const int* in_sizes, int n_in,
                              void* d_out, int out_size, void* d_ws, size_t ws_size,
                              hipStream_t stream) {
    const float* x = (const float*)d_in[0];
    const float* a = (const float*)d_in[1];
    const float* b = (const float*)d_in[2];
    // d_in[3] (c) is unused by the reference.
    float* out = (float*)d_out;

    const int S = S_FIXED;
    const int B = in_sizes[0] / (2 * S);
    const int nblocks = B * (S / TILE);

    gmp_mfma<<<dim3(nblocks), dim3(BLK), 0, stream>>>(x, a, b, out, S);
}